// Round 7
// baseline (83.581 us; speedup 1.0000x reference)
//
#include <hip/hip_runtime.h>
#include <math.h>

#define T_LEN 8192
#define EPSF  1e-6f

typedef __attribute__((ext_vector_type(8))) short short8;
typedef __attribute__((ext_vector_type(4))) float float4v;

// ---------------------------------------------------------------------------
// Single fused kernel. One block = (batch b, 256-row t-strip), 1024 blocks x
// 256 threads, __launch_bounds__(256,4): 4 blocks/CU, one residency round.
//
// R7 = R6 with the compile fix: __builtin_nontemporal_store requires a clang
// native vector type; use float4v (ext_vector_type(4) float) instead of
// HIP's float4 class. Output stores are NONTEMPORAL
// (global_store_dwordx4 ... nt): the 64-MiB write-once output stream no
// longer thrashes the 4-MiB-per-XCD L2 with write-allocate + dirty
// eviction. All arithmetic byte-identical to R5 (== 82.9us baseline).
//
// Phase 0/1 (one barrier): threads 0-63: shapelet global->reg, EXACT serial
//   two-pass znorm + bf16 hi/lo split -> LDS Bhi/Blo (permuted row
//   c = (p&3)*16 + p>>2) + lsum/ls2. threads 64-143: stage x window -> xs.
// Phase 1.5: window stats, one row per thread, verbatim math, float4 pack
//   {mu,inv,w2} -> lstat; B fragments + stats -> registers. barrier.
// Phase 2: per unit (staggered u order, wave+block offset): pair-packed A
//   from xs (v_perm_b32, bit-identical element math); 3-MFMA bf16 hi/lo
//   GEMM per pt (verbatim order); epilogue folds window znorm + exp,
//   nontemporal float4v stores. Rows t<32 / t>8160 are the zero padding.
// ---------------------------------------------------------------------------
__global__ __launch_bounds__(256, 4) void shapelet_fused(
        const float* __restrict__ x,
        const float* __restrict__ sh,
        float* __restrict__ out) {
    __shared__ unsigned short Bhi[64][72];     // 9 KB, 144 B rows (16B-aligned)
    __shared__ unsigned short Blo[64][72];     // 9 KB
    __shared__ __align__(16) float xs[320];    // x[t0-32 .. t0+287]
    __shared__ float4 lstat[256];              // {mu, inv, w2, -} per row
    __shared__ __align__(16) float lsum[64];   // logical-p order
    __shared__ __align__(16) float ls2[64];

    const int tid  = threadIdx.x;
    const int lane = tid & 63;
    const int wave = tid >> 6;
    const int n    = lane & 15;
    const int quad = lane >> 4;

    const int super = blockIdx.x & 31;         // 32 strips of 256 rows
    const int b     = blockIdx.x >> 5;         // 32 batches
    const int t0    = super << 8;

    // ---------------- phase 0/1: prep (global->reg) + xs staging ----------
    if (tid < 64) {
        const int p = tid;
        const int c = ((p & 3) << 4) + (p >> 2);   // permuted B row

        float S[64];
        const float4* s4 = (const float4*)(sh + (size_t)p * 64);
#pragma unroll
        for (int i = 0; i < 16; ++i) {
            float4 v = s4[i];
            S[4 * i + 0] = v.x;
            S[4 * i + 1] = v.y;
            S[4 * i + 2] = v.z;
            S[4 * i + 3] = v.w;
        }

        // EXACT prior-round prep arithmetic (same order, same ops).
        float s1 = 0.f;
#pragma unroll
        for (int l = 0; l < 64; ++l) s1 += S[l];
        float mu = s1 * (1.f / 64.f);
        float sq = 0.f;
#pragma unroll
        for (int l = 0; l < 64; ++l) { float d = S[l] - mu; sq = fmaf(d, d, sq); }
        float sd  = fmaxf(sqrtf(sq * (1.f / 64.f)), EPSF);
        float inv = 1.f / sd;
        float ssum = 0.f, ss2 = 0.f;
#pragma unroll
        for (int l2 = 0; l2 < 32; ++l2) {
            unsigned pk_h, pk_l;
            {   // element 2*l2 (low half)
                float v = S[2 * l2];
                float s = (v - mu) * inv;
                unsigned ub = __float_as_uint(s);
                float hi = __uint_as_float(ub & 0xFFFF0000u);
                float lo = s - hi;
                unsigned lb = __float_as_uint(lo) & 0xFFFF0000u;
                pk_h = ub >> 16;
                pk_l = lb >> 16;
                float eff = hi + __uint_as_float(lb);
                ssum += eff;
                ss2  = fmaf(eff, eff, ss2);
            }
            {   // element 2*l2+1 (high half)
                float v = S[2 * l2 + 1];
                float s = (v - mu) * inv;
                unsigned ub = __float_as_uint(s);
                float hi = __uint_as_float(ub & 0xFFFF0000u);
                float lo = s - hi;
                unsigned lb = __float_as_uint(lo) & 0xFFFF0000u;
                pk_h |= (ub & 0xFFFF0000u);
                pk_l |= lb;
                float eff = hi + __uint_as_float(lb);
                ssum += eff;
                ss2  = fmaf(eff, eff, ss2);
            }
            *(unsigned*)&Bhi[c][2 * l2] = pk_h;
            *(unsigned*)&Blo[c][2 * l2] = pk_l;
        }
        lsum[p] = ssum;
        ls2[p]  = ss2;
    } else if (tid < 144) {
        // stage x window into LDS (80 float4 = 320 floats)
        const int i = tid - 64;
        int g0 = t0 - 32 + (i << 2);
        float4 v;
        if (g0 >= 0 && g0 + 3 < T_LEN) {
            v = *(const float4*)(x + (size_t)b * T_LEN + g0);
        } else {
            float* vp = (float*)&v;
#pragma unroll
            for (int e = 0; e < 4; ++e) {
                int g = g0 + e;
                vp[e] = ((unsigned)g < (unsigned)T_LEN) ? x[(size_t)b * T_LEN + g] : 0.f;
            }
        }
        *(float4*)&xs[i << 2] = v;
    }
    __syncthreads();

    // ---------------- phase 1.5: window stats + fragment loads -------------
    {
        const int r = tid;
        float s1 = 0.f, sq = 0.f;
#pragma unroll
        for (int l = 0; l < 64; ++l) {
            float v = xs[r + l];
            s1 += v; sq = fmaf(v, v, sq);
        }
        float mu  = s1 * (1.f / 64.f);
        float var = fmaxf(sq * (1.f / 64.f) - mu * mu, 0.f);
        float sd  = fmaxf(sqrtf(var), EPSF);
        float inv = 1.f / sd;
        float4 st;
        st.x = mu;
        st.y = inv;
        st.z = 64.f * var * inv * inv;
        st.w = 0.f;
        lstat[r] = st;
    }

    // B fragments -> registers (layout identical to proven kernel):
    // lane holds B[k = quad*8+j + 32*h][col = lane&15]; permuted row
    // c = pt*16+n is logical shapelet 4n+pt.
    short8 Bh[4][2], Bl[4][2];
#pragma unroll
    for (int pt = 0; pt < 4; ++pt)
#pragma unroll
        for (int h = 0; h < 2; ++h) {
            Bh[pt][h] = *(const short8*)&Bhi[pt * 16 + n][h * 32 + (quad << 3)];
            Bl[pt][h] = *(const short8*)&Blo[pt * 16 + n][h * 32 + (quad << 3)];
        }
    const float4 sm4 = *(const float4*)&lsum[n << 2];   // logical 4n..4n+3
    const float4 sv4 = *(const float4*)&ls2[n << 2];
    __syncthreads();

    // ---------------- phase 2: MFMA main (staggered unit order) ------------
    const int stag = (wave + (int)blockIdx.x) & 3;

#pragma unroll
    for (int uu = 0; uu < 4; ++uu) {
        const int u = (uu + stag) & 3;

        // A fragments: A[m][k] = xs[u*64 + wave*16 + m + k]; pair-packed.
        const int abase = (u << 6) + (wave << 4) + n + (quad << 3);
        short8 Ah[2], Al[2];
#pragma unroll
        for (int h = 0; h < 2; ++h) {
            union { unsigned w[4]; short8 v; } ph, pl;
#pragma unroll
            for (int j2 = 0; j2 < 4; ++j2) {
                float v0 = xs[abase + h * 32 + 2 * j2];
                float v1 = xs[abase + h * 32 + 2 * j2 + 1];
                unsigned u0 = __float_as_uint(v0);
                unsigned u1 = __float_as_uint(v1);
                float l0 = v0 - __uint_as_float(u0 & 0xFFFF0000u);
                float l1 = v1 - __uint_as_float(u1 & 0xFFFF0000u);
                // dst = { u1.hi16 : u0.hi16 }  (low short = element 2*j2)
                ph.w[j2] = __builtin_amdgcn_perm(u1, u0, 0x07060302u);
                pl.w[j2] = __builtin_amdgcn_perm(__float_as_uint(l1),
                                                 __float_as_uint(l0), 0x07060302u);
            }
            Ah[h] = ph.v;
            Al[h] = pl.v;
        }

        float4v acc[4];
#pragma unroll
        for (int pt = 0; pt < 4; ++pt) {
            float4v a = {0.f, 0.f, 0.f, 0.f};
#pragma unroll
            for (int h = 0; h < 2; ++h) {
                a = __builtin_amdgcn_mfma_f32_16x16x32_bf16(Ah[h], Bh[pt][h], a, 0, 0, 0);
                a = __builtin_amdgcn_mfma_f32_16x16x32_bf16(Ah[h], Bl[pt][h], a, 0, 0, 0);
                a = __builtin_amdgcn_mfma_f32_16x16x32_bf16(Al[h], Bh[pt][h], a, 0, 0, 0);
            }
            acc[pt] = a;
        }

        // epilogue: fold window znorm + exp, NONTEMPORAL float4v store at
        // cols 4n..4n+3 (write-once stream; bypass L2 retention).
#pragma unroll
        for (int r = 0; r < 4; ++r) {
            // C/D layout: col = lane&15, row = quad*4 + r
            int tl = (u << 6) + (wave << 4) + (quad << 2) + r;
            int tg = t0 + tl;
            bool valid = (tg >= 32) && (tg <= 8160);
            float4 st = lstat[tl];
            float mu  = st.x;
            float inv = st.y;
            float w2  = st.z;
            float d0 = (acc[0][r] - mu * sm4.x) * inv;
            float d1 = (acc[1][r] - mu * sm4.y) * inv;
            float d2 = (acc[2][r] - mu * sm4.z) * inv;
            float d3 = (acc[3][r] - mu * sm4.w) * inv;
            float4v o;
            o.x = valid ? __expf(-(w2 + sv4.x - 2.f * d0)) : 0.f;
            o.y = valid ? __expf(-(w2 + sv4.y - 2.f * d1)) : 0.f;
            o.z = valid ? __expf(-(w2 + sv4.z - 2.f * d2)) : 0.f;
            o.w = valid ? __expf(-(w2 + sv4.w - 2.f * d3)) : 0.f;
            float4v* dst = (float4v*)(out + (((size_t)(b * T_LEN + tg)) << 6) + (n << 2));
            __builtin_nontemporal_store(o, dst);
        }
    }
}

extern "C" void kernel_launch(void* const* d_in, const int* in_sizes, int n_in,
                              void* d_out, int out_size, void* d_ws, size_t ws_size,
                              hipStream_t stream) {
    const float* x  = (const float*)d_in[0];   // (32, 8192, 1)
    const float* sh = (const float*)d_in[1];   // (64, 1, 64)
    float* out = (float*)d_out;                // (32, 8192, 64)

    shapelet_fused<<<32 * 32, 256, 0, stream>>>(x, sh, out);
}